// Round 3
// baseline (1622.481 us; speedup 1.0000x reference)
//
#include <hip/hip_runtime.h>
#include <hip/hip_bf16.h>
#include <cstdint>
#include <cstddef>

typedef __attribute__((ext_vector_type(8))) short short8;   // 8 x bf16 bits
typedef __attribute__((ext_vector_type(4))) float floatx4;  // MFMA C/D

#define MFMA_BF16(a, b, c) __builtin_amdgcn_mfma_f32_16x16x32_bf16((a), (b), (c), 0, 0, 0)

__device__ __forceinline__ short bf16bits(float v) {
  return __builtin_bit_cast(short, __float2bfloat16(v));
}

// Async 16B/lane global->LDS (m97: width=16). LDS dest = wave-uniform base +
// lane*16 (m104/m108). Source layout must match LDS layout in lane order.
__device__ __forceinline__ void stage16(const void* gp, void* lds_base) {
  __builtin_amdgcn_global_load_lds(
      (const __attribute__((address_space(1))) unsigned int*)(uintptr_t)gp,
      (__attribute__((address_space(3))) unsigned int*)(unsigned int)(uintptr_t)lds_base,
      16, 0, 0);
}

// ---------------------------------------------------------------------------
// fp32 -> bf16 elementwise (grid-stride, 8 elems/thread; n % 8 == 0).
// ---------------------------------------------------------------------------
__global__ __launch_bounds__(256) void cvt_bf16(
    const float* __restrict__ in, __hip_bfloat16* __restrict__ out, long n)
{
  const long stride = (long)gridDim.x * 256 * 8;
  for (long i = ((long)blockIdx.x * 256 + threadIdx.x) * 8; i < n; i += stride) {
    const floatx4 f0 = *(const floatx4*)(const void*)(in + i);
    const floatx4 f1 = *(const floatx4*)(const void*)(in + i + 4);
    short t[8];
#pragma unroll
    for (int j = 0; j < 4; ++j) { t[j] = bf16bits(f0[j]); t[4 + j] = bf16bits(f1[j]); }
    *(short8*)(void*)(out + i) = *(const short8*)(const void*)t;
  }
}

// ---------------------------------------------------------------------------
// 256x256 8-phase GEMM (T2+T3+T4+T5, m201 template): C = A[M][Kd] * B[N][Kd]^T.
// BK=64, 8 waves (2Mx4N), per-wave 128x64 output (acc[8][4]).
// LDS = 2 dbuf x 4 slots (B_k0,A_k0,B_k1,A_k1; each 256x32 bf16 = 16 KB) = 128 KB.
// Pipeline: prologue stages 7 half-tiles, vmcnt(6); per tile 4 phases, each
// {ds_read 4-8 x b128 | stage 1 half-tile -> barrier -> lgkmcnt(0) ->
//  setprio(1) 16 MFMA setprio(0) -> barrier}; boundary vmcnt(6) at phase 4
// (3 half-tiles stay in flight; drain to 0 only for the last two tiles).
// Safety: half h of tile t+2 is staged at local phase h+2; slot h's reads
// complete by phase h+1 (B_k0:p1, A_k0:p1-2, B_k1:p3, A_k1:p3-4) -> no WAR race.
// T2 swizzle: stored k-granule g2 ^= (row>>1)&3 -- applied identically on the
// pre-swizzled *global* source (linear LDS dest, rule #21) and on ds_read.
// EPI 0: fused QKV epilogue -- bx<16 -> Q(+RoPE), <20 -> K(+RoPE), else V.
// EPI 1: fp32 output (final projection).
// ---------------------------------------------------------------------------
template <int EPI, int Kd>
__global__ __launch_bounds__(512, 2) void gemm8p(
    const __hip_bfloat16* __restrict__ A,
    const __hip_bfloat16* __restrict__ B,
    __hip_bfloat16* __restrict__ Cq,
    __hip_bfloat16* __restrict__ Ck,
    __hip_bfloat16* __restrict__ Cvv,
    float* __restrict__ Cf,
    const float* __restrict__ cosf, const float* __restrict__ sinf)
{
  extern __shared__ __attribute__((aligned(16))) short lds[];  // 8 x 8192 shorts
  constexpr int NKT = Kd / 64;   // K-tiles
  constexpr int NH  = 4 * NKT;   // half-tiles total

  const int tid  = (int)threadIdx.x;
  const int wave = tid >> 6;
  const int lane = tid & 63;
  const int quad = lane >> 4;
  const int lc   = lane & 15;
  const int wm   = wave >> 2;    // 2 M-waves
  const int wn   = wave & 3;     // 4 N-waves
  const long tm0 = (long)blockIdx.y * 256;
  const long tn0 = (long)blockIdx.x * 256;

  // Staging precompute. LDS granule L = j*512 + tid -> row = j*128 + (tid>>2),
  // stored k-granule = tid&3. Pre-swizzled global k-granule g2 = (tid&3) ^
  // ((row>>1)&3); the +128 row offset of j=1 doesn't change (row>>1)&3.
  const int srow = tid >> 2;
  const int sg2  = (tid & 3) ^ ((srow >> 1) & 3);
  const __hip_bfloat16* const Ab_ = A + (size_t)(tm0 + srow) * Kd + sg2 * 8;
  const __hip_bfloat16* const Bb_ = B + (size_t)(tn0 + srow) * Kd + sg2 * 8;
  short* const sdst = lds + wave * 512;   // wave-uniform; lane*16B implicit

  // Read-side swizzle: row&7 reduces to lane bits -> per-lane constant.
  const int swz  = (quad ^ ((lc >> 1) & 3)) << 3;       // in shorts, 0/8/16/24
  const int aoff = (wm * 128 + lc) * 32 + swz;
  const int boff = (wn * 64 + lc) * 32 + swz;

  floatx4 acc[8][4];
#pragma unroll
  for (int i = 0; i < 8; ++i)
#pragma unroll
    for (int j = 0; j < 4; ++j) acc[i][j] = (floatx4){0.f, 0.f, 0.f, 0.f};

#define STAGE_HALF(n)                                                         \
  do {                                                                        \
    const int t_ = (n) >> 2, h_ = (n) & 3;                                    \
    const __hip_bfloat16* s_ = (h_ & 1) ? Ab_ : Bb_;                          \
    const int ko_ = t_ * 64 + (h_ >> 1) * 32;                                 \
    short* d_ = sdst + ((t_ & 1) * 4 + h_) * 8192;                            \
    stage16(s_ + ko_, d_);                                                    \
    stage16(s_ + ko_ + (size_t)128 * Kd, d_ + 4096);                          \
  } while (0)

  // Prologue: tile0 full + tile1 {B_k0,A_k0,B_k1}; vmcnt(6) -> tile0 landed.
#pragma unroll
  for (int n = 0; n < 7; ++n) STAGE_HALF(n);
  asm volatile("s_waitcnt vmcnt(6)" ::: "memory");
  __builtin_amdgcn_s_barrier();

  for (int t = 0; t < NKT; ++t) {
    const int buf4 = (t & 1) * 4;
    const short* const Bs0 = lds + (buf4 + 0) * 8192;
    const short* const As0 = lds + (buf4 + 1) * 8192;
    const short* const Bs1 = lds + (buf4 + 2) * 8192;
    const short* const As1 = lds + (buf4 + 3) * 8192;
    const int n0 = 4 * t + 7;
    short8 a[4], b[4], a2[4];

    // ---- phase 1: kh=0, m0-3 x n0-3 (8 ds_read) ----
#pragma unroll
    for (int mi = 0; mi < 4; ++mi) a[mi] = *(const short8*)(As0 + aoff + mi * 512);
#pragma unroll
    for (int ni = 0; ni < 4; ++ni) b[ni] = *(const short8*)(Bs0 + boff + ni * 512);
    if (n0 < NH) STAGE_HALF(n0);            // tile t+1, A_k1 (other buf)
    __builtin_amdgcn_s_barrier();
    asm volatile("s_waitcnt lgkmcnt(0)" ::: "memory");
    __builtin_amdgcn_s_setprio(1);
#pragma unroll
    for (int mi = 0; mi < 4; ++mi)
#pragma unroll
      for (int ni = 0; ni < 4; ++ni)
        acc[mi][ni] = MFMA_BF16(a[mi], b[ni], acc[mi][ni]);
    __builtin_amdgcn_s_setprio(0);
    __builtin_amdgcn_s_barrier();

    // ---- phase 2: kh=0, m4-7 x n0-3 (4 ds_read, reuse b) ----
#pragma unroll
    for (int mi = 0; mi < 4; ++mi) a2[mi] = *(const short8*)(As0 + aoff + (mi + 4) * 512);
    if (n0 + 1 < NH) STAGE_HALF(n0 + 1);    // tile t+2, B_k0 (this buf; done p1)
    __builtin_amdgcn_s_barrier();
    asm volatile("s_waitcnt lgkmcnt(0)" ::: "memory");
    __builtin_amdgcn_s_setprio(1);
#pragma unroll
    for (int mi = 0; mi < 4; ++mi)
#pragma unroll
      for (int ni = 0; ni < 4; ++ni)
        acc[mi + 4][ni] = MFMA_BF16(a2[mi], b[ni], acc[mi + 4][ni]);
    __builtin_amdgcn_s_setprio(0);
    __builtin_amdgcn_s_barrier();

    // ---- phase 3: kh=1, m0-3 x n0-3 (8 ds_read) ----
#pragma unroll
    for (int mi = 0; mi < 4; ++mi) a[mi] = *(const short8*)(As1 + aoff + mi * 512);
#pragma unroll
    for (int ni = 0; ni < 4; ++ni) b[ni] = *(const short8*)(Bs1 + boff + ni * 512);
    if (n0 + 2 < NH) STAGE_HALF(n0 + 2);    // tile t+2, A_k0 (done p1-p2)
    __builtin_amdgcn_s_barrier();
    asm volatile("s_waitcnt lgkmcnt(0)" ::: "memory");
    __builtin_amdgcn_s_setprio(1);
#pragma unroll
    for (int mi = 0; mi < 4; ++mi)
#pragma unroll
      for (int ni = 0; ni < 4; ++ni)
        acc[mi][ni] = MFMA_BF16(a[mi], b[ni], acc[mi][ni]);
    __builtin_amdgcn_s_setprio(0);
    __builtin_amdgcn_s_barrier();

    // ---- phase 4: kh=1, m4-7 x n0-3 (4 ds_read) ----
#pragma unroll
    for (int mi = 0; mi < 4; ++mi) a2[mi] = *(const short8*)(As1 + aoff + (mi + 4) * 512);
    if (n0 + 3 < NH) STAGE_HALF(n0 + 3);    // tile t+2, B_k1 (done p3)
    __builtin_amdgcn_s_barrier();
    asm volatile("s_waitcnt lgkmcnt(0)" ::: "memory");
    __builtin_amdgcn_s_setprio(1);
#pragma unroll
    for (int mi = 0; mi < 4; ++mi)
#pragma unroll
      for (int ni = 0; ni < 4; ++ni)
        acc[mi + 4][ni] = MFMA_BF16(a2[mi], b[ni], acc[mi + 4][ni]);
    __builtin_amdgcn_s_setprio(0);
    // Boundary: ensure tile t+1 fully landed; keep 3 half-tiles in flight.
    if (t + 2 < NKT) { asm volatile("s_waitcnt vmcnt(6)" ::: "memory"); }
    else             { asm volatile("s_waitcnt vmcnt(0)" ::: "memory"); }
    __builtin_amdgcn_s_barrier();
  }
#undef STAGE_HALF

  // Epilogue. C/D layout: col = lane&15, row = quad*4 + reg (m89/m91).
  const int bx = (int)blockIdx.x;
#pragma unroll
  for (int mi = 0; mi < 8; ++mi) {
    const long row0 = tm0 + wm * 128 + mi * 16 + quad * 4;
#pragma unroll
    for (int ni = 0; ni < 4; ++ni) {
      const long col = tn0 + wn * 64 + ni * 16 + lc;
#pragma unroll
      for (int r = 0; r < 4; ++r) {
        float v = acc[mi][ni][r];
        if (EPI == 0) {
          if (bx < 20) {  // Q or K tile: fused interleaved RoPE
            const float vp = __shfl_xor(v, 1);         // col-pair partner
            const int s  = (int)((row0 + r) & 2047);   // seq pos (S=2048)
            const int pi = ((int)col & 127) >> 1;      // pair idx within head
            const float cv = cosf[s * 64 + pi];
            const float sv = sinf[s * 64 + pi];
            v = (lc & 1) ? (vp * sv + v * cv) : (v * cv - vp * sv);
          }
          if (bx < 16)
            Cq[(row0 + r) * 4096 + col] = __float2bfloat16(v);
          else if (bx < 20)
            Ck[(row0 + r) * 1024 + (col - 4096)] = __float2bfloat16(v);
          else
            Cvv[(row0 + r) * 1024 + (col - 5120)] = __float2bfloat16(v);
        } else {
          Cf[(row0 + r) * 4096 + col] = v;
        }
      }
    }
  }
}

// ---------------------------------------------------------------------------
// V (B,S,KV,HD) bf16 -> Vt (B,KV,HD,S) bf16, 32x32 tiles via LDS.
// ---------------------------------------------------------------------------
__global__ __launch_bounds__(256) void transpose_v(
    const __hip_bfloat16* __restrict__ V,
    __hip_bfloat16* __restrict__ Vt)
{
  constexpr int S = 2048, KVH = 8, HD = 128;
  __shared__ __hip_bfloat16 t[32][33];
  const int b = blockIdx.z >> 3, kv = blockIdx.z & 7;
  const int s0 = blockIdx.x * 32, d0 = blockIdx.y * 32;
  const int tx = threadIdx.x & 31, ty = threadIdx.x >> 5;  // 32 x 8
#pragma unroll
  for (int i = 0; i < 4; ++i) {
    const int s = s0 + ty + i * 8;
    t[ty + i * 8][tx] = V[(((size_t)b * S + s) * KVH + kv) * HD + d0 + tx];
  }
  __syncthreads();
#pragma unroll
  for (int i = 0; i < 4; ++i) {
    const int d = d0 + ty + i * 8;
    Vt[(((size_t)b * KVH + kv) * HD + d) * S + s0 + tx] = t[tx][ty + i * 8];
  }
}

// ---------------------------------------------------------------------------
// Causal GQA flash attention. 1 block = (b,h,128-row Q tile), 4 waves; wave
// owns 32 Q rows. K-tile = 64. LDS k-block-major; Ps separate (48 KB total ->
// 3 blocks/CU; launch_bounds(256,3) caps VGPR ~170 vs ~150 live set).
// T14 pipeline: tile kt+1's K/V global loads are issued right after barrier
// (B), hiding HBM/L2 latency under tile kt's QK/softmax/PV.
// Ps layout: row-stride 64 shorts, granule XOR swizzle slot=(col>>3)^(row&7),
// same involution on write and short8 read (verified round 2).
// NOTE: O may alias Q (block reads its Q rows into regs before writing O;
// row sets are block-disjoint) — no __restrict__ on Q/O.
// ---------------------------------------------------------------------------
__global__ __launch_bounds__(256, 3) void flash_causal(
    const __hip_bfloat16* Q,
    const __hip_bfloat16* __restrict__ K,
    const __hip_bfloat16* __restrict__ Vt,
    __hip_bfloat16* O)
{
  constexpr int S = 2048, H = 32, KVH = 8, HD = 128;
  constexpr float NEG = -30000.0f;
  __shared__ __align__(16) short Ks[16 * 64 * 8];   // 16 KB
  __shared__ __align__(16) short Vs[8 * 128 * 8];   // 16 KB
  __shared__ __align__(16) short Ps[128 * 64];      // 16 KB (XOR-swizzled)

  const int qt = (int)(gridDim.x - 1u - blockIdx.x);  // heavy tiles first
  const int h = blockIdx.y, b = blockIdx.z;
  const int kvh = h >> 2;                             // GQA n_rep = 4
  const int tid = threadIdx.x, wave = tid >> 6, lane = tid & 63;
  const int quad = lane >> 4, lc = lane & 15;
  const int q0 = qt * 128;
  const float scale = 0.08838834764831845f;           // 1/sqrt(128)

  short8 qf[2][4];
#pragma unroll
  for (int i = 0; i < 2; ++i) {
    const __hip_bfloat16* qp =
        Q + (((size_t)b * S + q0 + wave * 32 + i * 16 + lc) * H + h) * HD + quad * 8;
#pragma unroll
    for (int kd = 0; kd < 4; ++kd)
      qf[i][kd] = *(const short8*)(const void*)(qp + kd * 32);
  }

  floatx4 Oa[2][8];
#pragma unroll
  for (int i = 0; i < 2; ++i)
#pragma unroll
    for (int jd = 0; jd < 8; ++jd) Oa[i][jd] = (floatx4){0.f, 0.f, 0.f, 0.f};
  float mrun[2][4], lrun[2][4];
#pragma unroll
  for (int i = 0; i < 2; ++i)
#pragma unroll
    for (int r = 0; r < 4; ++r) { mrun[i][r] = NEG; lrun[i][r] = 0.f; }

  const size_t kg_base = (size_t)b * S * (KVH * HD) + (size_t)kvh * HD;
  const size_t vg_base = ((size_t)b * KVH + kvh) * (size_t)HD * S;

  const int kw = tid & 3, srow = tid >> 2;   // K staging: 64 rows x 4 d-chunks
  const int vw = tid & 1, drow = tid >> 1;   // V staging: 128 rows x 2 s-chunks
  const __hip_bfloat16* const kp0 =
      K + kg_base + (size_t)srow * (KVH * HD) + kw * 32;
  const __hip_bfloat16* const vp0 =
      Vt + vg_base + (size_t)drow * S + vw * 32;

  const int nkt = 2 * qt + 2;
  short8 kr[4], vr[4];
  // Prologue: issue tile 0 loads.
#pragma unroll
  for (int j = 0; j < 4; ++j) kr[j] = *(const short8*)(const void*)(kp0 + j * 8);
#pragma unroll
  for (int j = 0; j < 4; ++j) vr[j] = *(const short8*)(const void*)(vp0 + j * 8);

  for (int kt = 0; kt < nkt; ++kt) {
    const int kbase = kt * 64;
    __syncthreads();                 // (A) previous tile fully consumed
#pragma unroll
    for (int j = 0; j < 4; ++j)
      *(short8*)(Ks + ((kw * 4 + j) * 64 + srow) * 8) = kr[j];
#pragma unroll
    for (int j = 0; j < 4; ++j)
      *(short8*)(Vs + ((vw * 4 + j) * 128 + drow) * 8) = vr[j];
    __syncthreads();                 // (B) staging visible

    // T14: issue NEXT tile's global loads now; latency hides under compute.
    if (kt + 1 < nkt) {
      const __hip_bfloat16* kp = kp0 + (size_t)(kbase + 64) * (KVH * HD);
      const __hip_bfloat16* vp = vp0 + (kbase + 64);
#pragma unroll
      for (int j = 0; j < 4; ++j) kr[j] = *(const short8*)(const void*)(kp + j * 8);
#pragma unroll
      for (int j = 0; j < 4; ++j) vr[j] = *(const short8*)(const void*)(vp + j * 8);
    }

    const bool active = (kbase <= q0 + wave * 32 + 31);
    const bool needmask = (kbase + 63 > q0 + wave * 32);

    if (active) {
      floatx4 sa[2][4];
#pragma unroll
      for (int i = 0; i < 2; ++i)
#pragma unroll
        for (int j = 0; j < 4; ++j) sa[i][j] = (floatx4){0.f, 0.f, 0.f, 0.f};
      // S = Q K^T
      __builtin_amdgcn_s_setprio(1);
#pragma unroll
      for (int jc = 0; jc < 4; ++jc) {
        short8 bfr[4];
#pragma unroll
        for (int kd = 0; kd < 4; ++kd)
          bfr[kd] = *(const short8*)(Ks + ((kd * 4 + quad) * 64 + jc * 16 + lc) * 8);
#pragma unroll
        for (int i = 0; i < 2; ++i)
#pragma unroll
          for (int kd = 0; kd < 4; ++kd)
            sa[i][jc] = MFMA_BF16(qf[i][kd], bfr[kd], sa[i][jc]);
      }
      __builtin_amdgcn_s_setprio(0);

      // Online softmax per row (raw-score domain; scale folded into exp arg).
#pragma unroll
      for (int i = 0; i < 2; ++i) {
        const int rbase = q0 + wave * 32 + i * 16 + quad * 4;
        float mloc[4] = {NEG, NEG, NEG, NEG};
        if (needmask) {
#pragma unroll
          for (int jc = 0; jc < 4; ++jc) {
            const int colg = kbase + jc * 16 + lc;
#pragma unroll
            for (int r = 0; r < 4; ++r) {
              float v = sa[i][jc][r];
              v = (colg > rbase + r) ? NEG : v;        // causal mask
              sa[i][jc][r] = v;
              mloc[r] = fmaxf(mloc[r], v);
            }
          }
        } else {
#pragma unroll
          for (int jc = 0; jc < 4; ++jc)
#pragma unroll
            for (int r = 0; r < 4; ++r) mloc[r] = fmaxf(mloc[r], sa[i][jc][r]);
        }
#pragma unroll
        for (int off = 1; off < 16; off <<= 1)
#pragma unroll
          for (int r = 0; r < 4; ++r)
            mloc[r] = fmaxf(mloc[r], __shfl_xor(mloc[r], off));
        float alpha[4], lsum[4] = {0.f, 0.f, 0.f, 0.f};
#pragma unroll
        for (int r = 0; r < 4; ++r) {
          const float mn = fmaxf(mrun[i][r], mloc[r]);
          alpha[r] = __expf((mrun[i][r] - mn) * scale);
          mrun[i][r] = mn;
        }
#pragma unroll
        for (int jc = 0; jc < 4; ++jc)
#pragma unroll
          for (int r = 0; r < 4; ++r) {
            const float p = __expf((sa[i][jc][r] - mrun[i][r]) * scale);
            sa[i][jc][r] = p;
            lsum[r] += p;
          }
#pragma unroll
        for (int off = 1; off < 16; off <<= 1)
#pragma unroll
          for (int r = 0; r < 4; ++r) lsum[r] += __shfl_xor(lsum[r], off);
#pragma unroll
        for (int r = 0; r < 4; ++r) lrun[i][r] = lrun[i][r] * alpha[r] + lsum[r];
#pragma unroll
        for (int jd = 0; jd < 8; ++jd)
#pragma unroll
          for (int r = 0; r < 4; ++r) Oa[i][jd][r] *= alpha[r];
        // Write P rows (own wave's 32 rows only; stride 64, XOR-swizzled).
#pragma unroll
        for (int jc = 0; jc < 4; ++jc)
#pragma unroll
          for (int r = 0; r < 4; ++r) {
            const int prow = wave * 32 + i * 16 + quad * 4 + r;
            const int pcol = jc * 16 + lc;
            const int slot = (pcol >> 3) ^ (prow & 7);
            Ps[prow * 64 + slot * 8 + (pcol & 7)] = bf16bits(sa[i][jc][r]);
          }
      }
      __asm__ __volatile__("s_waitcnt lgkmcnt(0)" ::: "memory");

      // O += P V
      short8 pf[2][2];
#pragma unroll
      for (int i = 0; i < 2; ++i)
#pragma unroll
        for (int ks2 = 0; ks2 < 2; ++ks2) {
          const int prow = wave * 32 + i * 16 + lc;
          const int slot = (ks2 * 4 + quad) ^ (prow & 7);
          pf[i][ks2] = *(const short8*)(Ps + prow * 64 + slot * 8);
        }
      __builtin_amdgcn_s_setprio(1);
#pragma unroll
      for (int jd = 0; jd < 8; ++jd) {
        const int d = jd * 16 + lc;
        short8 vf[2];
#pragma unroll
        for (int ks2 = 0; ks2 < 2; ++ks2)
          vf[ks2] = *(const short8*)(Vs + ((ks2 * 4 + quad) * 128 + d) * 8);
#pragma unroll
        for (int i = 0; i < 2; ++i)
#pragma unroll
          for (int ks2 = 0; ks2 < 2; ++ks2)
            Oa[i][jd] = MFMA_BF16(pf[i][ks2], vf[ks2], Oa[i][jd]);
      }
      __builtin_amdgcn_s_setprio(0);
    }
  }

  // Normalize and write O in (B,S,H,HD) bf16.
#pragma unroll
  for (int i = 0; i < 2; ++i)
#pragma unroll
    for (int r = 0; r < 4; ++r) {
      const int rq = q0 + wave * 32 + i * 16 + quad * 4 + r;
      const float inv = 1.f / lrun[i][r];
      __hip_bfloat16* op = O + (((size_t)b * S + rq) * H + h) * HD + lc;
#pragma unroll
      for (int jd = 0; jd < 8; ++jd)
        op[jd * 16] = __float2bfloat16(Oa[i][jd][r] * inv);
    }
}

// ---------------------------------------------------------------------------
extern "C" void kernel_launch(void* const* d_in, const int* in_sizes, int n_in,
                              void* d_out, int out_size, void* d_ws, size_t ws_size,
                              hipStream_t stream) {
  constexpr int S = 2048, D = 4096, H = 32, KVH = 8, HD = 128;
  constexpr size_t M = (size_t)2 * S;           // 4096 rows (B*S)
  constexpr size_t NQ = (size_t)H * HD;         // 4096
  constexpr size_t NKV = (size_t)KVH * HD;      // 1024
  (void)in_sizes; (void)n_in; (void)out_size; (void)ws_size;

  const float* x  = (const float*)d_in[0];
  const float* wq = (const float*)d_in[1];
  const float* wk = (const float*)d_in[2];
  const float* wv = (const float*)d_in[3];
  const float* wo = (const float*)d_in[4];
  const float* cs = (const float*)d_in[5];
  const float* sn = (const float*)d_in[6];
  float* out = (float*)d_out;

  // Workspace layout (bf16 elems). wob aliases xb (xb dead after QKV GEMM);
  // Ab aliases Qb (flash O rows are block-local re-writes of its own Q rows).
  __hip_bfloat16* ws    = (__hip_bfloat16*)d_ws;
  __hip_bfloat16* xb    = ws;                         // M*D        = 16.78M
  __hip_bfloat16* wob   = ws;                         // alias of xb
  __hip_bfloat16* wqkvb = xb + M * D;                 // 6144*D     = 25.17M
  __hip_bfloat16* Qb    = wqkvb + 6144 * (size_t)D;   // M*NQ       = 16.78M
  __hip_bfloat16* Ab    = Qb;                         // alias of Qb
  __hip_bfloat16* Kb    = Qb + M * NQ;                // M*NKV      =  4.19M
  __hip_bfloat16* Vb    = Kb + M * NKV;               // M*NKV
  __hip_bfloat16* Vtb   = Vb + M * NKV;               // M*NKV      (~143 MB total)

  // 128 KiB dynamic LDS opt-in (one-time; host-side, graph-capture safe).
  static bool lds_attr_done = false;
  if (!lds_attr_done) {
    hipFuncSetAttribute(reinterpret_cast<const void*>(&gemm8p<0, 4096>),
                        hipFuncAttributeMaxDynamicSharedMemorySize, 131072);
    hipFuncSetAttribute(reinterpret_cast<const void*>(&gemm8p<1, 4096>),
                        hipFuncAttributeMaxDynamicSharedMemorySize, 131072);
    lds_attr_done = true;
  }

  dim3 blk(256);
  // fp32 -> bf16 conversions (pure BW, ~60 us total)
  cvt_bf16<<<1024, blk, 0, stream>>>(x,  xb,                    (long)(M * D));
  cvt_bf16<<<1024, blk, 0, stream>>>(wq, wqkvb,                 (long)(NQ * D));
  cvt_bf16<<<512,  blk, 0, stream>>>(wk, wqkvb + NQ * D,        (long)(NKV * D));
  cvt_bf16<<<512,  blk, 0, stream>>>(wv, wqkvb + (NQ + NKV) * D,(long)(NKV * D));

  // Fused QKV projection + RoPE (M=4096, N=6144), 256^2 8-phase
  gemm8p<0, 4096><<<dim3(24, 16), dim3(512), 131072, stream>>>(
      xb, wqkvb, Qb, Kb, Vb, nullptr, cs, sn);
  // wo conversion (after QKV GEMM: xb is dead, wob aliases it)
  cvt_bf16<<<1024, blk, 0, stream>>>(wo, wob, (long)(NQ * D));

  transpose_v<<<dim3(64, 4, 16), blk, 0, stream>>>(Vb, Vtb);
  flash_causal<<<dim3(16, 32, 2), blk, 0, stream>>>(Qb, Kb, Vtb, Ab);

  // Output projection (bf16 x bf16 -> fp32 out), 256^2 8-phase
  gemm8p<1, 4096><<<dim3(16, 16), dim3(512), 131072, stream>>>(
      Ab, wob, nullptr, nullptr, nullptr, out, nullptr, nullptr);
}

// Round 4
// 858.987 us; speedup vs baseline: 1.8888x; 1.8888x over previous
//
#include <hip/hip_runtime.h>
#include <hip/hip_bf16.h>
#include <cstdint>
#include <cstddef>

typedef __attribute__((ext_vector_type(8))) short short8;   // 8 x bf16 bits
typedef __attribute__((ext_vector_type(4))) float floatx4;  // MFMA C/D

#define MFMA_BF16(a, b, c) __builtin_amdgcn_mfma_f32_16x16x32_bf16((a), (b), (c), 0, 0, 0)

__device__ __forceinline__ short bf16bits(float v) {
  return __builtin_bit_cast(short, __float2bfloat16(v));
}

// Async 16B/lane global->LDS (m97: width=16). LDS dest = wave-uniform base +
// lane*16 (m104/m108). Source layout must match LDS layout in lane order.
__device__ __forceinline__ void stage16(const void* gp, void* lds_base) {
  __builtin_amdgcn_global_load_lds(
      (const __attribute__((address_space(1))) unsigned int*)(uintptr_t)gp,
      (__attribute__((address_space(3))) unsigned int*)(unsigned int)(uintptr_t)lds_base,
      16, 0, 0);
}

// ---------------------------------------------------------------------------
// fp32 -> bf16 elementwise (grid-stride, 8 elems/thread; n % 8 == 0).
// ---------------------------------------------------------------------------
__global__ __launch_bounds__(256) void cvt_bf16(
    const float* __restrict__ in, __hip_bfloat16* __restrict__ out, long n)
{
  const long stride = (long)gridDim.x * 256 * 8;
  for (long i = ((long)blockIdx.x * 256 + threadIdx.x) * 8; i < n; i += stride) {
    const floatx4 f0 = *(const floatx4*)(const void*)(in + i);
    const floatx4 f1 = *(const floatx4*)(const void*)(in + i + 4);
    short t[8];
#pragma unroll
    for (int j = 0; j < 4; ++j) { t[j] = bf16bits(f0[j]); t[4 + j] = bf16bits(f1[j]); }
    *(short8*)(void*)(out + i) = *(const short8*)(const void*)t;
  }
}

// ---------------------------------------------------------------------------
// 256x256 8-phase GEMM (T2+T3+T4+T5, m201 template): C = A[M][Kd] * B[N][Kd]^T.
// BK=64, 8 waves (2Mx4N), per-wave 128x64 output (acc[8][4]).
// LDS = 2 dbuf x 4 slots (B_k0,A_k0,B_k1,A_k1; each 256x32 bf16 = 16 KB) = 128 KB.
// Pipeline: prologue stages 7 half-tiles, vmcnt(6); per tile 4 phases, each
// {ds_read 4-8 x b128 | stage 1 half-tile -> barrier -> lgkmcnt(0) ->
//  setprio(1) 16 MFMA setprio(0) -> barrier}; boundary vmcnt(6) at phase 4
// (3 half-tiles stay in flight; drain to 0 only for the last two tiles).
// Safety: half h of tile t+2 is staged at local phase h+2; slot h's reads
// complete by phase h+1 (B_k0:p1, A_k0:p1-2, B_k1:p3, A_k1:p3-4) -> no WAR race.
// T2 swizzle: stored k-granule g2 ^= (row>>1)&3 -- applied identically on the
// pre-swizzled *global* source (linear LDS dest, rule #21) and on ds_read.
// EPI 0: fused QKV epilogue -- bx<16 -> Q(+RoPE), <20 -> K(+RoPE), else V.
// EPI 1: fp32 output (final projection).
// ---------------------------------------------------------------------------
template <int EPI, int Kd>
__global__ __launch_bounds__(512, 2) void gemm8p(
    const __hip_bfloat16* __restrict__ A,
    const __hip_bfloat16* __restrict__ B,
    __hip_bfloat16* __restrict__ Cq,
    __hip_bfloat16* __restrict__ Ck,
    __hip_bfloat16* __restrict__ Cvv,
    float* __restrict__ Cf,
    const float* __restrict__ cosf, const float* __restrict__ sinf)
{
  extern __shared__ __attribute__((aligned(16))) short lds[];  // 8 x 8192 shorts
  constexpr int NKT = Kd / 64;   // K-tiles
  constexpr int NH  = 4 * NKT;   // half-tiles total

  const int tid  = (int)threadIdx.x;
  const int wave = tid >> 6;
  const int lane = tid & 63;
  const int quad = lane >> 4;
  const int lc   = lane & 15;
  const int wm   = wave >> 2;    // 2 M-waves
  const int wn   = wave & 3;     // 4 N-waves
  const long tm0 = (long)blockIdx.y * 256;
  const long tn0 = (long)blockIdx.x * 256;

  // Staging precompute. LDS granule L = j*512 + tid -> row = j*128 + (tid>>2),
  // stored k-granule = tid&3. Pre-swizzled global k-granule g2 = (tid&3) ^
  // ((row>>1)&3); the +128 row offset of j=1 doesn't change (row>>1)&3.
  const int srow = tid >> 2;
  const int sg2  = (tid & 3) ^ ((srow >> 1) & 3);
  const __hip_bfloat16* const Ab_ = A + (size_t)(tm0 + srow) * Kd + sg2 * 8;
  const __hip_bfloat16* const Bb_ = B + (size_t)(tn0 + srow) * Kd + sg2 * 8;
  short* const sdst = lds + wave * 512;   // wave-uniform; lane*16B implicit

  // Read-side swizzle: row&7 reduces to lane bits -> per-lane constant.
  const int swz  = (quad ^ ((lc >> 1) & 3)) << 3;       // in shorts, 0/8/16/24
  const int aoff = (wm * 128 + lc) * 32 + swz;
  const int boff = (wn * 64 + lc) * 32 + swz;

  floatx4 acc[8][4];
#pragma unroll
  for (int i = 0; i < 8; ++i)
#pragma unroll
    for (int j = 0; j < 4; ++j) acc[i][j] = (floatx4){0.f, 0.f, 0.f, 0.f};

#define STAGE_HALF(n)                                                         \
  do {                                                                        \
    const int t_ = (n) >> 2, h_ = (n) & 3;                                    \
    const __hip_bfloat16* s_ = (h_ & 1) ? Ab_ : Bb_;                          \
    const int ko_ = t_ * 64 + (h_ >> 1) * 32;                                 \
    short* d_ = sdst + ((t_ & 1) * 4 + h_) * 8192;                            \
    stage16(s_ + ko_, d_);                                                    \
    stage16(s_ + ko_ + (size_t)128 * Kd, d_ + 4096);                          \
  } while (0)

  // Prologue: tile0 full + tile1 {B_k0,A_k0,B_k1}; vmcnt(6) -> tile0 landed.
#pragma unroll
  for (int n = 0; n < 7; ++n) STAGE_HALF(n);
  asm volatile("s_waitcnt vmcnt(6)" ::: "memory");
  __builtin_amdgcn_s_barrier();

  for (int t = 0; t < NKT; ++t) {
    const int buf4 = (t & 1) * 4;
    const short* const Bs0 = lds + (buf4 + 0) * 8192;
    const short* const As0 = lds + (buf4 + 1) * 8192;
    const short* const Bs1 = lds + (buf4 + 2) * 8192;
    const short* const As1 = lds + (buf4 + 3) * 8192;
    const int n0 = 4 * t + 7;
    short8 a[4], b[4], a2[4];

    // ---- phase 1: kh=0, m0-3 x n0-3 (8 ds_read) ----
#pragma unroll
    for (int mi = 0; mi < 4; ++mi) a[mi] = *(const short8*)(As0 + aoff + mi * 512);
#pragma unroll
    for (int ni = 0; ni < 4; ++ni) b[ni] = *(const short8*)(Bs0 + boff + ni * 512);
    if (n0 < NH) STAGE_HALF(n0);            // tile t+1, A_k1 (other buf)
    __builtin_amdgcn_s_barrier();
    asm volatile("s_waitcnt lgkmcnt(0)" ::: "memory");
    __builtin_amdgcn_s_setprio(1);
#pragma unroll
    for (int mi = 0; mi < 4; ++mi)
#pragma unroll
      for (int ni = 0; ni < 4; ++ni)
        acc[mi][ni] = MFMA_BF16(a[mi], b[ni], acc[mi][ni]);
    __builtin_amdgcn_s_setprio(0);
    __builtin_amdgcn_s_barrier();

    // ---- phase 2: kh=0, m4-7 x n0-3 (4 ds_read, reuse b) ----
#pragma unroll
    for (int mi = 0; mi < 4; ++mi) a2[mi] = *(const short8*)(As0 + aoff + (mi + 4) * 512);
    if (n0 + 1 < NH) STAGE_HALF(n0 + 1);    // tile t+2, B_k0 (this buf; done p1)
    __builtin_amdgcn_s_barrier();
    asm volatile("s_waitcnt lgkmcnt(0)" ::: "memory");
    __builtin_amdgcn_s_setprio(1);
#pragma unroll
    for (int mi = 0; mi < 4; ++mi)
#pragma unroll
      for (int ni = 0; ni < 4; ++ni)
        acc[mi + 4][ni] = MFMA_BF16(a2[mi], b[ni], acc[mi + 4][ni]);
    __builtin_amdgcn_s_setprio(0);
    __builtin_amdgcn_s_barrier();

    // ---- phase 3: kh=1, m0-3 x n0-3 (8 ds_read) ----
#pragma unroll
    for (int mi = 0; mi < 4; ++mi) a[mi] = *(const short8*)(As1 + aoff + mi * 512);
#pragma unroll
    for (int ni = 0; ni < 4; ++ni) b[ni] = *(const short8*)(Bs1 + boff + ni * 512);
    if (n0 + 2 < NH) STAGE_HALF(n0 + 2);    // tile t+2, A_k0 (done p1-p2)
    __builtin_amdgcn_s_barrier();
    asm volatile("s_waitcnt lgkmcnt(0)" ::: "memory");
    __builtin_amdgcn_s_setprio(1);
#pragma unroll
    for (int mi = 0; mi < 4; ++mi)
#pragma unroll
      for (int ni = 0; ni < 4; ++ni)
        acc[mi][ni] = MFMA_BF16(a[mi], b[ni], acc[mi][ni]);
    __builtin_amdgcn_s_setprio(0);
    __builtin_amdgcn_s_barrier();

    // ---- phase 4: kh=1, m4-7 x n0-3 (4 ds_read) ----
#pragma unroll
    for (int mi = 0; mi < 4; ++mi) a2[mi] = *(const short8*)(As1 + aoff + (mi + 4) * 512);
    if (n0 + 3 < NH) STAGE_HALF(n0 + 3);    // tile t+2, B_k1 (done p3)
    __builtin_amdgcn_s_barrier();
    asm volatile("s_waitcnt lgkmcnt(0)" ::: "memory");
    __builtin_amdgcn_s_setprio(1);
#pragma unroll
    for (int mi = 0; mi < 4; ++mi)
#pragma unroll
      for (int ni = 0; ni < 4; ++ni)
        acc[mi + 4][ni] = MFMA_BF16(a2[mi], b[ni], acc[mi + 4][ni]);
    __builtin_amdgcn_s_setprio(0);
    // Boundary: ensure tile t+1 fully landed; keep 3 half-tiles in flight.
    if (t + 2 < NKT) { asm volatile("s_waitcnt vmcnt(6)" ::: "memory"); }
    else             { asm volatile("s_waitcnt vmcnt(0)" ::: "memory"); }
    __builtin_amdgcn_s_barrier();
  }
#undef STAGE_HALF

  // Epilogue. C/D layout: col = lane&15, row = quad*4 + reg (m89/m91).
  const int bx = (int)blockIdx.x;
#pragma unroll
  for (int mi = 0; mi < 8; ++mi) {
    const long row0 = tm0 + wm * 128 + mi * 16 + quad * 4;
#pragma unroll
    for (int ni = 0; ni < 4; ++ni) {
      const long col = tn0 + wn * 64 + ni * 16 + lc;
#pragma unroll
      for (int r = 0; r < 4; ++r) {
        float v = acc[mi][ni][r];
        if (EPI == 0) {
          if (bx < 20) {  // Q or K tile: fused interleaved RoPE
            const float vp = __shfl_xor(v, 1);         // col-pair partner
            const int s  = (int)((row0 + r) & 2047);   // seq pos (S=2048)
            const int pi = ((int)col & 127) >> 1;      // pair idx within head
            const float cv = cosf[s * 64 + pi];
            const float sv = sinf[s * 64 + pi];
            v = (lc & 1) ? (vp * sv + v * cv) : (v * cv - vp * sv);
          }
          if (bx < 16)
            Cq[(row0 + r) * 4096 + col] = __float2bfloat16(v);
          else if (bx < 20)
            Ck[(row0 + r) * 1024 + (col - 4096)] = __float2bfloat16(v);
          else
            Cvv[(row0 + r) * 1024 + (col - 5120)] = __float2bfloat16(v);
        } else {
          Cf[(row0 + r) * 4096 + col] = v;
        }
      }
    }
  }
}

// ---------------------------------------------------------------------------
// V (B,S,KV,HD) bf16 -> Vt (B,KV,HD,S) bf16, 32x32 tiles via LDS.
// ---------------------------------------------------------------------------
__global__ __launch_bounds__(256) void transpose_v(
    const __hip_bfloat16* __restrict__ V,
    __hip_bfloat16* __restrict__ Vt)
{
  constexpr int S = 2048, KVH = 8, HD = 128;
  __shared__ __hip_bfloat16 t[32][33];
  const int b = blockIdx.z >> 3, kv = blockIdx.z & 7;
  const int s0 = blockIdx.x * 32, d0 = blockIdx.y * 32;
  const int tx = threadIdx.x & 31, ty = threadIdx.x >> 5;  // 32 x 8
#pragma unroll
  for (int i = 0; i < 4; ++i) {
    const int s = s0 + ty + i * 8;
    t[ty + i * 8][tx] = V[(((size_t)b * S + s) * KVH + kv) * HD + d0 + tx];
  }
  __syncthreads();
#pragma unroll
  for (int i = 0; i < 4; ++i) {
    const int d = d0 + ty + i * 8;
    Vt[(((size_t)b * KVH + kv) * HD + d) * S + s0 + tx] = t[tx][ty + i * 8];
  }
}

// ---------------------------------------------------------------------------
// Causal GQA flash attention, QBLK=64, complementary-pair scheduling.
// Block p in 0..15 processes q-tile (31-p) then q-tile p sequentially ->
// every block does exactly 33 K-tile units (perfect balance; 1024 equal
// blocks). 4 waves; wave owns 16 Q rows; every wave active in every K-tile.
// K-tile = 64. LDS: Ks 16K + Vs 16K + Ps 8K = 40 KB. NO launch_bounds min
// (rounds 2/3: forcing VGPR below the ~140 live set causes scratch spills).
// T14: next tile's K/V global loads issued right after barrier (B).
// Ps: stride 64 shorts, granule XOR swizzle slot = (pcol>>3) ^ g(prow),
// g(prow) = (prow ^ (prow>>3)) & 7 -- same involution on write and read.
// NOTE: O may alias Q (block writes only its own q-tiles' O rows, and reads
// each tile's Q rows before writing them) — no __restrict__ on Q/O.
// ---------------------------------------------------------------------------
__global__ __launch_bounds__(256) void flash_causal(
    const __hip_bfloat16* Q,
    const __hip_bfloat16* __restrict__ K,
    const __hip_bfloat16* __restrict__ Vt,
    __hip_bfloat16* O)
{
  constexpr int S = 2048, H = 32, KVH = 8, HD = 128;
  constexpr int NT = 32;                            // 64-row q-tiles
  constexpr float NEG = -30000.0f;
  __shared__ __align__(16) short Ks[16 * 64 * 8];   // 16 KB
  __shared__ __align__(16) short Vs[8 * 128 * 8];   // 16 KB
  __shared__ __align__(16) short Ps[64 * 64];       //  8 KB (XOR-swizzled)

  const int p = (int)blockIdx.x;                    // pair index 0..15
  const int h = blockIdx.y, b = blockIdx.z;
  const int kvh = h >> 2;                           // GQA n_rep = 4
  const int tid = threadIdx.x, wave = tid >> 6, lane = tid & 63;
  const int quad = lane >> 4, lc = lane & 15;
  const float scale = 0.08838834764831845f;         // 1/sqrt(128)

  const size_t kg_base = (size_t)b * S * (KVH * HD) + (size_t)kvh * HD;
  const size_t vg_base = ((size_t)b * KVH + kvh) * (size_t)HD * S;

  const int kw = tid & 3, srow = tid >> 2;   // K staging: 64 rows x 4 d-chunks
  const int vw = tid & 1, drow = tid >> 1;   // V staging: 128 rows x 2 s-chunks
  const __hip_bfloat16* const kp0 =
      K + kg_base + (size_t)srow * (KVH * HD) + kw * 32;
  const __hip_bfloat16* const vp0 =
      Vt + vg_base + (size_t)drow * S + vw * 32;

#pragma unroll 1
  for (int half = 0; half < 2; ++half) {
    const int qt = half ? p : (NT - 1 - p);         // heavy tile first
    const int q0 = qt * 64;
    const int nkt = qt + 1;

    short8 qf[4];
    {
      const __hip_bfloat16* qp =
          Q + (((size_t)b * S + q0 + wave * 16 + lc) * H + h) * HD + quad * 8;
#pragma unroll
      for (int kd = 0; kd < 4; ++kd)
        qf[kd] = *(const short8*)(const void*)(qp + kd * 32);
    }

    floatx4 Oa[8];
#pragma unroll
    for (int jd = 0; jd < 8; ++jd) Oa[jd] = (floatx4){0.f, 0.f, 0.f, 0.f};
    float mrun[4], lrun[4];
#pragma unroll
    for (int r = 0; r < 4; ++r) { mrun[r] = NEG; lrun[r] = 0.f; }

    short8 kr[4], vr[4];
    // Prologue: issue tile 0 loads.
#pragma unroll
    for (int j = 0; j < 4; ++j) kr[j] = *(const short8*)(const void*)(kp0 + j * 8);
#pragma unroll
    for (int j = 0; j < 4; ++j) vr[j] = *(const short8*)(const void*)(vp0 + j * 8);

#pragma unroll 1
    for (int kt = 0; kt < nkt; ++kt) {
      const int kbase = kt * 64;
      __syncthreads();                 // (A) previous tile fully consumed
#pragma unroll
      for (int j = 0; j < 4; ++j)
        *(short8*)(Ks + ((kw * 4 + j) * 64 + srow) * 8) = kr[j];
#pragma unroll
      for (int j = 0; j < 4; ++j)
        *(short8*)(Vs + ((vw * 4 + j) * 128 + drow) * 8) = vr[j];
      __syncthreads();                 // (B) staging visible

      // T14: issue NEXT tile's global loads; latency hides under compute.
      if (kt + 1 < nkt) {
        const __hip_bfloat16* kp = kp0 + (size_t)(kbase + 64) * (KVH * HD);
        const __hip_bfloat16* vp = vp0 + (kbase + 64);
#pragma unroll
        for (int j = 0; j < 4; ++j) kr[j] = *(const short8*)(const void*)(kp + j * 8);
#pragma unroll
        for (int j = 0; j < 4; ++j) vr[j] = *(const short8*)(const void*)(vp + j * 8);
      }

      // S = Q K^T  (wave's 16 rows x 64 keys)
      floatx4 sa[4];
#pragma unroll
      for (int jc = 0; jc < 4; ++jc) sa[jc] = (floatx4){0.f, 0.f, 0.f, 0.f};
      __builtin_amdgcn_s_setprio(1);
#pragma unroll
      for (int jc = 0; jc < 4; ++jc) {
        short8 bfr[4];
#pragma unroll
        for (int kd = 0; kd < 4; ++kd)
          bfr[kd] = *(const short8*)(Ks + ((kd * 4 + quad) * 64 + jc * 16 + lc) * 8);
#pragma unroll
        for (int kd = 0; kd < 4; ++kd)
          sa[jc] = MFMA_BF16(qf[kd], bfr[kd], sa[jc]);
      }
      __builtin_amdgcn_s_setprio(0);

      // Online softmax (raw-score domain; scale folded into exp arg).
      const int rbase = q0 + wave * 16 + quad * 4;
      const bool needmask = (kbase + 63 > q0 + wave * 16);  // diagonal tile
      float mloc[4] = {NEG, NEG, NEG, NEG};
      if (needmask) {
#pragma unroll
        for (int jc = 0; jc < 4; ++jc) {
          const int colg = kbase + jc * 16 + lc;
#pragma unroll
          for (int r = 0; r < 4; ++r) {
            float v = sa[jc][r];
            v = (colg > rbase + r) ? NEG : v;        // causal mask
            sa[jc][r] = v;
            mloc[r] = fmaxf(mloc[r], v);
          }
        }
      } else {
#pragma unroll
        for (int jc = 0; jc < 4; ++jc)
#pragma unroll
          for (int r = 0; r < 4; ++r) mloc[r] = fmaxf(mloc[r], sa[jc][r]);
      }
#pragma unroll
      for (int off = 1; off < 16; off <<= 1)
#pragma unroll
        for (int r = 0; r < 4; ++r)
          mloc[r] = fmaxf(mloc[r], __shfl_xor(mloc[r], off));
      float alpha[4], lsum[4] = {0.f, 0.f, 0.f, 0.f};
#pragma unroll
      for (int r = 0; r < 4; ++r) {
        const float mn = fmaxf(mrun[r], mloc[r]);
        alpha[r] = __expf((mrun[r] - mn) * scale);
        mrun[r] = mn;
      }
#pragma unroll
      for (int jc = 0; jc < 4; ++jc)
#pragma unroll
        for (int r = 0; r < 4; ++r) {
          const float pv = __expf((sa[jc][r] - mrun[r]) * scale);
          sa[jc][r] = pv;
          lsum[r] += pv;
        }
#pragma unroll
      for (int off = 1; off < 16; off <<= 1)
#pragma unroll
        for (int r = 0; r < 4; ++r) lsum[r] += __shfl_xor(lsum[r], off);
#pragma unroll
      for (int r = 0; r < 4; ++r) lrun[r] = lrun[r] * alpha[r] + lsum[r];
#pragma unroll
      for (int jd = 0; jd < 8; ++jd)
#pragma unroll
        for (int r = 0; r < 4; ++r) Oa[jd][r] *= alpha[r];

      // Write P (own wave's 16 rows; stride 64, XOR-swizzled granules).
#pragma unroll
      for (int jc = 0; jc < 4; ++jc)
#pragma unroll
        for (int r = 0; r < 4; ++r) {
          const int prow = wave * 16 + quad * 4 + r;
          const int pcol = jc * 16 + lc;
          const int slot = (pcol >> 3) ^ ((prow ^ (prow >> 3)) & 7);
          Ps[prow * 64 + slot * 8 + (pcol & 7)] = bf16bits(sa[jc][r]);
        }
      __asm__ __volatile__("s_waitcnt lgkmcnt(0)" ::: "memory");

      // O += P V
      short8 pf[2];
#pragma unroll
      for (int ks2 = 0; ks2 < 2; ++ks2) {
        const int prow = wave * 16 + lc;
        const int slot = (ks2 * 4 + quad) ^ ((prow ^ (prow >> 3)) & 7);
        pf[ks2] = *(const short8*)(Ps + prow * 64 + slot * 8);
      }
      __builtin_amdgcn_s_setprio(1);
#pragma unroll
      for (int jd = 0; jd < 8; ++jd) {
        const int d = jd * 16 + lc;
        short8 vf[2];
#pragma unroll
        for (int ks2 = 0; ks2 < 2; ++ks2)
          vf[ks2] = *(const short8*)(Vs + ((ks2 * 4 + quad) * 128 + d) * 8);
#pragma unroll
        for (int ks2 = 0; ks2 < 2; ++ks2)
          Oa[jd] = MFMA_BF16(pf[ks2], vf[ks2], Oa[jd]);
      }
      __builtin_amdgcn_s_setprio(0);
    }

    // Normalize and write this tile's O rows in (B,S,H,HD) bf16.
#pragma unroll
    for (int r = 0; r < 4; ++r) {
      const int rq = q0 + wave * 16 + quad * 4 + r;
      const float inv = 1.f / lrun[r];
      __hip_bfloat16* op = O + (((size_t)b * S + rq) * H + h) * HD + lc;
#pragma unroll
      for (int jd = 0; jd < 8; ++jd)
        op[jd * 16] = __float2bfloat16(Oa[jd][r] * inv);
    }
  }
}

// ---------------------------------------------------------------------------
extern "C" void kernel_launch(void* const* d_in, const int* in_sizes, int n_in,
                              void* d_out, int out_size, void* d_ws, size_t ws_size,
                              hipStream_t stream) {
  constexpr int S = 2048, D = 4096, H = 32, KVH = 8, HD = 128;
  constexpr size_t M = (size_t)2 * S;           // 4096 rows (B*S)
  constexpr size_t NQ = (size_t)H * HD;         // 4096
  constexpr size_t NKV = (size_t)KVH * HD;      // 1024
  (void)in_sizes; (void)n_in; (void)out_size; (void)ws_size;

  const float* x  = (const float*)d_in[0];
  const float* wq = (const float*)d_in[1];
  const float* wk = (const float*)d_in[2];
  const float* wv = (const float*)d_in[3];
  const float* wo = (const float*)d_in[4];
  const float* cs = (const float*)d_in[5];
  const float* sn = (const float*)d_in[6];
  float* out = (float*)d_out;

  // Workspace layout (bf16 elems). wob aliases xb (xb dead after QKV GEMM);
  // Ab aliases Qb (flash O rows are block-local re-writes of its own Q rows).
  __hip_bfloat16* ws    = (__hip_bfloat16*)d_ws;
  __hip_bfloat16* xb    = ws;                         // M*D        = 16.78M
  __hip_bfloat16* wob   = ws;                         // alias of xb
  __hip_bfloat16* wqkvb = xb + M * D;                 // 6144*D     = 25.17M
  __hip_bfloat16* Qb    = wqkvb + 6144 * (size_t)D;   // M*NQ       = 16.78M
  __hip_bfloat16* Ab    = Qb;                         // alias of Qb
  __hip_bfloat16* Kb    = Qb + M * NQ;                // M*NKV      =  4.19M
  __hip_bfloat16* Vb    = Kb + M * NKV;               // M*NKV
  __hip_bfloat16* Vtb   = Vb + M * NKV;               // M*NKV      (~143 MB total)

  // 128 KiB dynamic LDS opt-in (one-time; host-side, graph-capture safe).
  static bool lds_attr_done = false;
  if (!lds_attr_done) {
    hipFuncSetAttribute(reinterpret_cast<const void*>(&gemm8p<0, 4096>),
                        hipFuncAttributeMaxDynamicSharedMemorySize, 131072);
    hipFuncSetAttribute(reinterpret_cast<const void*>(&gemm8p<1, 4096>),
                        hipFuncAttributeMaxDynamicSharedMemorySize, 131072);
    lds_attr_done = true;
  }

  dim3 blk(256);
  // fp32 -> bf16 conversions (pure BW, ~60 us total)
  cvt_bf16<<<1024, blk, 0, stream>>>(x,  xb,                    (long)(M * D));
  cvt_bf16<<<1024, blk, 0, stream>>>(wq, wqkvb,                 (long)(NQ * D));
  cvt_bf16<<<512,  blk, 0, stream>>>(wk, wqkvb + NQ * D,        (long)(NKV * D));
  cvt_bf16<<<512,  blk, 0, stream>>>(wv, wqkvb + (NQ + NKV) * D,(long)(NKV * D));

  // Fused QKV projection + RoPE (M=4096, N=6144), 256^2 8-phase
  gemm8p<0, 4096><<<dim3(24, 16), dim3(512), 131072, stream>>>(
      xb, wqkvb, Qb, Kb, Vb, nullptr, cs, sn);
  // wo conversion (after QKV GEMM: xb is dead, wob aliases it)
  cvt_bf16<<<1024, blk, 0, stream>>>(wo, wob, (long)(NQ * D));

  transpose_v<<<dim3(64, 4, 16), blk, 0, stream>>>(Vb, Vtb);
  flash_causal<<<dim3(16, 32, 2), blk, 0, stream>>>(Qb, Kb, Vtb, Ab);

  // Output projection (bf16 x bf16 -> fp32 out), 256^2 8-phase
  gemm8p<1, 4096><<<dim3(16, 16), dim3(512), 131072, stream>>>(
      Ab, wob, nullptr, nullptr, nullptr, out, nullptr, nullptr);
}

// Round 5
// 824.678 us; speedup vs baseline: 1.9674x; 1.0416x over previous
//
#include <hip/hip_runtime.h>
#include <hip/hip_bf16.h>
#include <cstdint>
#include <cstddef>

typedef __attribute__((ext_vector_type(8))) short short8;   // 8 x bf16 bits
typedef __attribute__((ext_vector_type(4))) float floatx4;  // MFMA C/D

#define MFMA_BF16(a, b, c) __builtin_amdgcn_mfma_f32_16x16x32_bf16((a), (b), (c), 0, 0, 0)

__device__ __forceinline__ short bf16bits(float v) {
  return __builtin_bit_cast(short, __float2bfloat16(v));
}

// Async 16B/lane global->LDS (m97: width=16). LDS dest = wave-uniform base +
// lane*16 (m104/m108). Source layout must match LDS layout in lane order.
__device__ __forceinline__ void stage16(const void* gp, void* lds_base) {
  __builtin_amdgcn_global_load_lds(
      (const __attribute__((address_space(1))) unsigned int*)(uintptr_t)gp,
      (__attribute__((address_space(3))) unsigned int*)(unsigned int)(uintptr_t)lds_base,
      16, 0, 0);
}

// ---------------------------------------------------------------------------
// fp32 -> bf16 elementwise (grid-stride, 8 elems/thread; n % 8 == 0).
// ---------------------------------------------------------------------------
__global__ __launch_bounds__(256) void cvt_bf16(
    const float* __restrict__ in, __hip_bfloat16* __restrict__ out, long n)
{
  const long stride = (long)gridDim.x * 256 * 8;
  for (long i = ((long)blockIdx.x * 256 + threadIdx.x) * 8; i < n; i += stride) {
    const floatx4 f0 = *(const floatx4*)(const void*)(in + i);
    const floatx4 f1 = *(const floatx4*)(const void*)(in + i + 4);
    short t[8];
#pragma unroll
    for (int j = 0; j < 4; ++j) { t[j] = bf16bits(f0[j]); t[4 + j] = bf16bits(f1[j]); }
    *(short8*)(void*)(out + i) = *(const short8*)(const void*)t;
  }
}

// ---------------------------------------------------------------------------
// 256x256 8-phase GEMM (T2+T3+T4+T5, m201 template): C = A[M][Kd] * B[N][Kd]^T.
// BK=64, 8 waves (2Mx4N), per-wave 128x64 output (acc[8][4]).
// LDS = 2 dbuf x 4 slots (B_k0,A_k0,B_k1,A_k1; each 256x32 bf16 = 16 KB) = 128 KB.
// Pipeline: prologue stages 7 half-tiles, vmcnt(6); per tile 4 phases, each
// {ds_read 4-8 x b128 | stage 1 half-tile -> barrier -> lgkmcnt(0) ->
//  setprio(1) 16 MFMA setprio(0) -> barrier}.
// Wait schedule (round-5: relaxed two-wait): with the single boundary
// vmcnt(6), the youngest prefetch (A_k1(t+1), issued ph1 of tile t) had only
// 3 phases of slack -> stalls when staging misses L2 (FETCH 2.5x ideal on the
// QKV shape). Now TWO waits per K-tile, each vmcnt(10) (7 pairs in flight =
// 14 loads; force oldest 2 pairs):
//   end-ph2: forces B_k1(t), A_k1(t)   (read by ph3)  -> 5-6 phases slack
//   end-ph4: forces B_k0(t+1), A_k0(t+1) (read by ph1) -> 5-6 phases slack
// Inductive invariant: entering tile t outstanding =
//   [B1(t),A1(t),B0(t+1),A0(t+1),B1(t+1)]  (5 pairs).
// Tail (t+2>=NKT): vmcnt(0) fallback (over-wait, safe).
// WAR safety unchanged: half h of tile t+2 staged at phase h+2; slot h's
// reads complete by phase h+1 under the end-of-phase barriers.
// T2 swizzle: stored k-granule g2 ^= (row>>1)&3 -- applied identically on the
// pre-swizzled *global* source (linear LDS dest, rule #21) and on ds_read.
// EPI 0: fused QKV epilogue -- bx<16 -> Q(+RoPE), <20 -> K(+RoPE), else V.
// EPI 1: fp32 output (final projection).
// ---------------------------------------------------------------------------
template <int EPI, int Kd>
__global__ __launch_bounds__(512, 2) void gemm8p(
    const __hip_bfloat16* __restrict__ A,
    const __hip_bfloat16* __restrict__ B,
    __hip_bfloat16* __restrict__ Cq,
    __hip_bfloat16* __restrict__ Ck,
    __hip_bfloat16* __restrict__ Cvv,
    float* __restrict__ Cf,
    const float* __restrict__ cosf, const float* __restrict__ sinf)
{
  extern __shared__ __attribute__((aligned(16))) short lds[];  // 8 x 8192 shorts
  constexpr int NKT = Kd / 64;   // K-tiles
  constexpr int NH  = 4 * NKT;   // half-tiles total

  const int tid  = (int)threadIdx.x;
  const int wave = tid >> 6;
  const int lane = tid & 63;
  const int quad = lane >> 4;
  const int lc   = lane & 15;
  const int wm   = wave >> 2;    // 2 M-waves
  const int wn   = wave & 3;     // 4 N-waves
  const long tm0 = (long)blockIdx.y * 256;
  const long tn0 = (long)blockIdx.x * 256;

  // Staging precompute. LDS granule L = j*512 + tid -> row = j*128 + (tid>>2),
  // stored k-granule = tid&3. Pre-swizzled global k-granule g2 = (tid&3) ^
  // ((row>>1)&3); the +128 row offset of j=1 doesn't change (row>>1)&3.
  const int srow = tid >> 2;
  const int sg2  = (tid & 3) ^ ((srow >> 1) & 3);
  const __hip_bfloat16* const Ab_ = A + (size_t)(tm0 + srow) * Kd + sg2 * 8;
  const __hip_bfloat16* const Bb_ = B + (size_t)(tn0 + srow) * Kd + sg2 * 8;
  short* const sdst = lds + wave * 512;   // wave-uniform; lane*16B implicit

  // Read-side swizzle: row&7 reduces to lane bits -> per-lane constant.
  const int swz  = (quad ^ ((lc >> 1) & 3)) << 3;       // in shorts, 0/8/16/24
  const int aoff = (wm * 128 + lc) * 32 + swz;
  const int boff = (wn * 64 + lc) * 32 + swz;

  floatx4 acc[8][4];
#pragma unroll
  for (int i = 0; i < 8; ++i)
#pragma unroll
    for (int j = 0; j < 4; ++j) acc[i][j] = (floatx4){0.f, 0.f, 0.f, 0.f};

#define STAGE_HALF(n)                                                         \
  do {                                                                        \
    const int t_ = (n) >> 2, h_ = (n) & 3;                                    \
    const __hip_bfloat16* s_ = (h_ & 1) ? Ab_ : Bb_;                          \
    const int ko_ = t_ * 64 + (h_ >> 1) * 32;                                 \
    short* d_ = sdst + ((t_ & 1) * 4 + h_) * 8192;                            \
    stage16(s_ + ko_, d_);                                                    \
    stage16(s_ + ko_ + (size_t)128 * Kd, d_ + 4096);                          \
  } while (0)

  // Prologue: tile0 full + tile1 {B_k0,A_k0,B_k1}; vmcnt(6) -> tile0 landed.
#pragma unroll
  for (int n = 0; n < 7; ++n) STAGE_HALF(n);
  asm volatile("s_waitcnt vmcnt(6)" ::: "memory");
  __builtin_amdgcn_s_barrier();

  for (int t = 0; t < NKT; ++t) {
    const int buf4 = (t & 1) * 4;
    const short* const Bs0 = lds + (buf4 + 0) * 8192;
    const short* const As0 = lds + (buf4 + 1) * 8192;
    const short* const Bs1 = lds + (buf4 + 2) * 8192;
    const short* const As1 = lds + (buf4 + 3) * 8192;
    const int n0 = 4 * t + 7;
    short8 a[4], b[4], a2[4];

    // ---- phase 1: kh=0, m0-3 x n0-3 (8 ds_read) ----
#pragma unroll
    for (int mi = 0; mi < 4; ++mi) a[mi] = *(const short8*)(As0 + aoff + mi * 512);
#pragma unroll
    for (int ni = 0; ni < 4; ++ni) b[ni] = *(const short8*)(Bs0 + boff + ni * 512);
    if (n0 < NH) STAGE_HALF(n0);            // tile t+1, A_k1 (other buf)
    __builtin_amdgcn_s_barrier();
    asm volatile("s_waitcnt lgkmcnt(0)" ::: "memory");
    __builtin_amdgcn_s_setprio(1);
#pragma unroll
    for (int mi = 0; mi < 4; ++mi)
#pragma unroll
      for (int ni = 0; ni < 4; ++ni)
        acc[mi][ni] = MFMA_BF16(a[mi], b[ni], acc[mi][ni]);
    __builtin_amdgcn_s_setprio(0);
    __builtin_amdgcn_s_barrier();

    // ---- phase 2: kh=0, m4-7 x n0-3 (4 ds_read, reuse b) ----
#pragma unroll
    for (int mi = 0; mi < 4; ++mi) a2[mi] = *(const short8*)(As0 + aoff + (mi + 4) * 512);
    if (n0 + 1 < NH) STAGE_HALF(n0 + 1);    // tile t+2, B_k0 (this buf; done p1)
    __builtin_amdgcn_s_barrier();
    asm volatile("s_waitcnt lgkmcnt(0)" ::: "memory");
    __builtin_amdgcn_s_setprio(1);
#pragma unroll
    for (int mi = 0; mi < 4; ++mi)
#pragma unroll
      for (int ni = 0; ni < 4; ++ni)
        acc[mi + 4][ni] = MFMA_BF16(a2[mi], b[ni], acc[mi + 4][ni]);
    __builtin_amdgcn_s_setprio(0);
    // Mid-tile wait: force B_k1(t), A_k1(t) landed for phase 3/4 reads.
    if (t + 2 < NKT) { asm volatile("s_waitcnt vmcnt(10)" ::: "memory"); }
    else             { asm volatile("s_waitcnt vmcnt(0)"  ::: "memory"); }
    __builtin_amdgcn_s_barrier();

    // ---- phase 3: kh=1, m0-3 x n0-3 (8 ds_read) ----
#pragma unroll
    for (int mi = 0; mi < 4; ++mi) a[mi] = *(const short8*)(As1 + aoff + mi * 512);
#pragma unroll
    for (int ni = 0; ni < 4; ++ni) b[ni] = *(const short8*)(Bs1 + boff + ni * 512);
    if (n0 + 2 < NH) STAGE_HALF(n0 + 2);    // tile t+2, A_k0 (done p1-p2)
    __builtin_amdgcn_s_barrier();
    asm volatile("s_waitcnt lgkmcnt(0)" ::: "memory");
    __builtin_amdgcn_s_setprio(1);
#pragma unroll
    for (int mi = 0; mi < 4; ++mi)
#pragma unroll
      for (int ni = 0; ni < 4; ++ni)
        acc[mi][ni] = MFMA_BF16(a[mi], b[ni], acc[mi][ni]);
    __builtin_amdgcn_s_setprio(0);
    __builtin_amdgcn_s_barrier();

    // ---- phase 4: kh=1, m4-7 x n0-3 (4 ds_read) ----
#pragma unroll
    for (int mi = 0; mi < 4; ++mi) a2[mi] = *(const short8*)(As1 + aoff + (mi + 4) * 512);
    if (n0 + 3 < NH) STAGE_HALF(n0 + 3);    // tile t+2, B_k1 (done p3)
    __builtin_amdgcn_s_barrier();
    asm volatile("s_waitcnt lgkmcnt(0)" ::: "memory");
    __builtin_amdgcn_s_setprio(1);
#pragma unroll
    for (int mi = 0; mi < 4; ++mi)
#pragma unroll
      for (int ni = 0; ni < 4; ++ni)
        acc[mi + 4][ni] = MFMA_BF16(a2[mi], b[ni], acc[mi + 4][ni]);
    __builtin_amdgcn_s_setprio(0);
    // Boundary wait: force B_k0(t+1), A_k0(t+1) landed for phase 1/2 reads.
    if (t + 2 < NKT) { asm volatile("s_waitcnt vmcnt(10)" ::: "memory"); }
    else             { asm volatile("s_waitcnt vmcnt(0)"  ::: "memory"); }
    __builtin_amdgcn_s_barrier();
  }
#undef STAGE_HALF

  // Epilogue. C/D layout: col = lane&15, row = quad*4 + reg (m89/m91).
  const int bx = (int)blockIdx.x;
#pragma unroll
  for (int mi = 0; mi < 8; ++mi) {
    const long row0 = tm0 + wm * 128 + mi * 16 + quad * 4;
#pragma unroll
    for (int ni = 0; ni < 4; ++ni) {
      const long col = tn0 + wn * 64 + ni * 16 + lc;
#pragma unroll
      for (int r = 0; r < 4; ++r) {
        float v = acc[mi][ni][r];
        if (EPI == 0) {
          if (bx < 20) {  // Q or K tile: fused interleaved RoPE
            const float vp = __shfl_xor(v, 1);         // col-pair partner
            const int s  = (int)((row0 + r) & 2047);   // seq pos (S=2048)
            const int pi = ((int)col & 127) >> 1;      // pair idx within head
            const float cv = cosf[s * 64 + pi];
            const float sv = sinf[s * 64 + pi];
            v = (lc & 1) ? (vp * sv + v * cv) : (v * cv - vp * sv);
          }
          if (bx < 16)
            Cq[(row0 + r) * 4096 + col] = __float2bfloat16(v);
          else if (bx < 20)
            Ck[(row0 + r) * 1024 + (col - 4096)] = __float2bfloat16(v);
          else
            Cvv[(row0 + r) * 1024 + (col - 5120)] = __float2bfloat16(v);
        } else {
          Cf[(row0 + r) * 4096 + col] = v;
        }
      }
    }
  }
}

// ---------------------------------------------------------------------------
// V (B,S,KV,HD) bf16 -> Vt (B,KV,HD,S) bf16, 32x32 tiles via LDS.
// ---------------------------------------------------------------------------
__global__ __launch_bounds__(256) void transpose_v(
    const __hip_bfloat16* __restrict__ V,
    __hip_bfloat16* __restrict__ Vt)
{
  constexpr int S = 2048, KVH = 8, HD = 128;
  __shared__ __hip_bfloat16 t[32][33];
  const int b = blockIdx.z >> 3, kv = blockIdx.z & 7;
  const int s0 = blockIdx.x * 32, d0 = blockIdx.y * 32;
  const int tx = threadIdx.x & 31, ty = threadIdx.x >> 5;  // 32 x 8
#pragma unroll
  for (int i = 0; i < 4; ++i) {
    const int s = s0 + ty + i * 8;
    t[ty + i * 8][tx] = V[(((size_t)b * S + s) * KVH + kv) * HD + d0 + tx];
  }
  __syncthreads();
#pragma unroll
  for (int i = 0; i < 4; ++i) {
    const int d = d0 + ty + i * 8;
    Vt[(((size_t)b * KVH + kv) * HD + d) * S + s0 + tx] = t[tx][ty + i * 8];
  }
}

// ---------------------------------------------------------------------------
// Causal GQA flash attention, QBLK=64, complementary-pair scheduling.
// Block p in 0..15 processes q-tile (31-p) then q-tile p sequentially ->
// every block does exactly 33 K-tile units (perfect balance; 1024 equal
// blocks). 4 waves; wave owns 16 Q rows; every wave active in every K-tile.
// K-tile = 64. LDS: Ks 16K + Vs 16K + Ps 8K = 40 KB. NO launch_bounds min
// (rounds 2/3: forcing VGPR below the ~140 live set causes scratch spills).
// T14: next tile's K/V global loads issued right after barrier (B).
// Ps: stride 64 shorts, granule XOR swizzle slot = (pcol>>3) ^ g(prow),
// g(prow) = (prow ^ (prow>>3)) & 7 -- same involution on write and read.
// NOTE: O may alias Q (block writes only its own q-tiles' O rows, and reads
// each tile's Q rows before writing them) — no __restrict__ on Q/O.
// ---------------------------------------------------------------------------
__global__ __launch_bounds__(256) void flash_causal(
    const __hip_bfloat16* Q,
    const __hip_bfloat16* __restrict__ K,
    const __hip_bfloat16* __restrict__ Vt,
    __hip_bfloat16* O)
{
  constexpr int S = 2048, H = 32, KVH = 8, HD = 128;
  constexpr int NT = 32;                            // 64-row q-tiles
  constexpr float NEG = -30000.0f;
  __shared__ __align__(16) short Ks[16 * 64 * 8];   // 16 KB
  __shared__ __align__(16) short Vs[8 * 128 * 8];   // 16 KB
  __shared__ __align__(16) short Ps[64 * 64];       //  8 KB (XOR-swizzled)

  const int p = (int)blockIdx.x;                    // pair index 0..15
  const int h = blockIdx.y, b = blockIdx.z;
  const int kvh = h >> 2;                           // GQA n_rep = 4
  const int tid = threadIdx.x, wave = tid >> 6, lane = tid & 63;
  const int quad = lane >> 4, lc = lane & 15;
  const float scale = 0.08838834764831845f;         // 1/sqrt(128)

  const size_t kg_base = (size_t)b * S * (KVH * HD) + (size_t)kvh * HD;
  const size_t vg_base = ((size_t)b * KVH + kvh) * (size_t)HD * S;

  const int kw = tid & 3, srow = tid >> 2;   // K staging: 64 rows x 4 d-chunks
  const int vw = tid & 1, drow = tid >> 1;   // V staging: 128 rows x 2 s-chunks
  const __hip_bfloat16* const kp0 =
      K + kg_base + (size_t)srow * (KVH * HD) + kw * 32;
  const __hip_bfloat16* const vp0 =
      Vt + vg_base + (size_t)drow * S + vw * 32;

#pragma unroll 1
  for (int half = 0; half < 2; ++half) {
    const int qt = half ? p : (NT - 1 - p);         // heavy tile first
    const int q0 = qt * 64;
    const int nkt = qt + 1;

    short8 qf[4];
    {
      const __hip_bfloat16* qp =
          Q + (((size_t)b * S + q0 + wave * 16 + lc) * H + h) * HD + quad * 8;
#pragma unroll
      for (int kd = 0; kd < 4; ++kd)
        qf[kd] = *(const short8*)(const void*)(qp + kd * 32);
    }

    floatx4 Oa[8];
#pragma unroll
    for (int jd = 0; jd < 8; ++jd) Oa[jd] = (floatx4){0.f, 0.f, 0.f, 0.f};
    float mrun[4], lrun[4];
#pragma unroll
    for (int r = 0; r < 4; ++r) { mrun[r] = NEG; lrun[r] = 0.f; }

    short8 kr[4], vr[4];
    // Prologue: issue tile 0 loads.
#pragma unroll
    for (int j = 0; j < 4; ++j) kr[j] = *(const short8*)(const void*)(kp0 + j * 8);
#pragma unroll
    for (int j = 0; j < 4; ++j) vr[j] = *(const short8*)(const void*)(vp0 + j * 8);

#pragma unroll 1
    for (int kt = 0; kt < nkt; ++kt) {
      const int kbase = kt * 64;
      __syncthreads();                 // (A) previous tile fully consumed
#pragma unroll
      for (int j = 0; j < 4; ++j)
        *(short8*)(Ks + ((kw * 4 + j) * 64 + srow) * 8) = kr[j];
#pragma unroll
      for (int j = 0; j < 4; ++j)
        *(short8*)(Vs + ((vw * 4 + j) * 128 + drow) * 8) = vr[j];
      __syncthreads();                 // (B) staging visible

      // T14: issue NEXT tile's global loads; latency hides under compute.
      if (kt + 1 < nkt) {
        const __hip_bfloat16* kp = kp0 + (size_t)(kbase + 64) * (KVH * HD);
        const __hip_bfloat16* vp = vp0 + (kbase + 64);
#pragma unroll
        for (int j = 0; j < 4; ++j) kr[j] = *(const short8*)(const void*)(kp + j * 8);
#pragma unroll
        for (int j = 0; j < 4; ++j) vr[j] = *(const short8*)(const void*)(vp + j * 8);
      }

      // S = Q K^T  (wave's 16 rows x 64 keys)
      floatx4 sa[4];
#pragma unroll
      for (int jc = 0; jc < 4; ++jc) sa[jc] = (floatx4){0.f, 0.f, 0.f, 0.f};
      __builtin_amdgcn_s_setprio(1);
#pragma unroll
      for (int jc = 0; jc < 4; ++jc) {
        short8 bfr[4];
#pragma unroll
        for (int kd = 0; kd < 4; ++kd)
          bfr[kd] = *(const short8*)(Ks + ((kd * 4 + quad) * 64 + jc * 16 + lc) * 8);
#pragma unroll
        for (int kd = 0; kd < 4; ++kd)
          sa[jc] = MFMA_BF16(qf[kd], bfr[kd], sa[jc]);
      }
      __builtin_amdgcn_s_setprio(0);

      // Online softmax (raw-score domain; scale folded into exp arg).
      const int rbase = q0 + wave * 16 + quad * 4;
      const bool needmask = (kbase + 63 > q0 + wave * 16);  // diagonal tile
      float mloc[4] = {NEG, NEG, NEG, NEG};
      if (needmask) {
#pragma unroll
        for (int jc = 0; jc < 4; ++jc) {
          const int colg = kbase + jc * 16 + lc;
#pragma unroll
          for (int r = 0; r < 4; ++r) {
            float v = sa[jc][r];
            v = (colg > rbase + r) ? NEG : v;        // causal mask
            sa[jc][r] = v;
            mloc[r] = fmaxf(mloc[r], v);
          }
        }
      } else {
#pragma unroll
        for (int jc = 0; jc < 4; ++jc)
#pragma unroll
          for (int r = 0; r < 4; ++r) mloc[r] = fmaxf(mloc[r], sa[jc][r]);
      }
#pragma unroll
      for (int off = 1; off < 16; off <<= 1)
#pragma unroll
        for (int r = 0; r < 4; ++r)
          mloc[r] = fmaxf(mloc[r], __shfl_xor(mloc[r], off));
      float alpha[4], lsum[4] = {0.f, 0.f, 0.f, 0.f};
#pragma unroll
      for (int r = 0; r < 4; ++r) {
        const float mn = fmaxf(mrun[r], mloc[r]);
        alpha[r] = __expf((mrun[r] - mn) * scale);
        mrun[r] = mn;
      }
#pragma unroll
      for (int jc = 0; jc < 4; ++jc)
#pragma unroll
        for (int r = 0; r < 4; ++r) {
          const float pv = __expf((sa[jc][r] - mrun[r]) * scale);
          sa[jc][r] = pv;
          lsum[r] += pv;
        }
#pragma unroll
      for (int off = 1; off < 16; off <<= 1)
#pragma unroll
        for (int r = 0; r < 4; ++r) lsum[r] += __shfl_xor(lsum[r], off);
#pragma unroll
      for (int r = 0; r < 4; ++r) lrun[r] = lrun[r] * alpha[r] + lsum[r];
#pragma unroll
      for (int jd = 0; jd < 8; ++jd)
#pragma unroll
        for (int r = 0; r < 4; ++r) Oa[jd][r] *= alpha[r];

      // Write P (own wave's 16 rows; stride 64, XOR-swizzled granules).
#pragma unroll
      for (int jc = 0; jc < 4; ++jc)
#pragma unroll
        for (int r = 0; r < 4; ++r) {
          const int prow = wave * 16 + quad * 4 + r;
          const int pcol = jc * 16 + lc;
          const int slot = (pcol >> 3) ^ ((prow ^ (prow >> 3)) & 7);
          Ps[prow * 64 + slot * 8 + (pcol & 7)] = bf16bits(sa[jc][r]);
        }
      __asm__ __volatile__("s_waitcnt lgkmcnt(0)" ::: "memory");

      // O += P V
      short8 pf[2];
#pragma unroll
      for (int ks2 = 0; ks2 < 2; ++ks2) {
        const int prow = wave * 16 + lc;
        const int slot = (ks2 * 4 + quad) ^ ((prow ^ (prow >> 3)) & 7);
        pf[ks2] = *(const short8*)(Ps + prow * 64 + slot * 8);
      }
      __builtin_amdgcn_s_setprio(1);
#pragma unroll
      for (int jd = 0; jd < 8; ++jd) {
        const int d = jd * 16 + lc;
        short8 vf[2];
#pragma unroll
        for (int ks2 = 0; ks2 < 2; ++ks2)
          vf[ks2] = *(const short8*)(Vs + ((ks2 * 4 + quad) * 128 + d) * 8);
#pragma unroll
        for (int ks2 = 0; ks2 < 2; ++ks2)
          Oa[jd] = MFMA_BF16(pf[ks2], vf[ks2], Oa[jd]);
      }
      __builtin_amdgcn_s_setprio(0);
    }

    // Normalize and write this tile's O rows in (B,S,H,HD) bf16.
#pragma unroll
    for (int r = 0; r < 4; ++r) {
      const int rq = q0 + wave * 16 + quad * 4 + r;
      const float inv = 1.f / lrun[r];
      __hip_bfloat16* op = O + (((size_t)b * S + rq) * H + h) * HD + lc;
#pragma unroll
      for (int jd = 0; jd < 8; ++jd)
        op[jd * 16] = __float2bfloat16(Oa[jd][r] * inv);
    }
  }
}

// ---------------------------------------------------------------------------
extern "C" void kernel_launch(void* const* d_in, const int* in_sizes, int n_in,
                              void* d_out, int out_size, void* d_ws, size_t ws_size,
                              hipStream_t stream) {
  constexpr int S = 2048, D = 4096, H = 32, KVH = 8, HD = 128;
  constexpr size_t M = (size_t)2 * S;           // 4096 rows (B*S)
  constexpr size_t NQ = (size_t)H * HD;         // 4096
  constexpr size_t NKV = (size_t)KVH * HD;      // 1024
  (void)in_sizes; (void)n_in; (void)out_size; (void)ws_size;

  const float* x  = (const float*)d_in[0];
  const float* wq = (const float*)d_in[1];
  const float* wk = (const float*)d_in[2];
  const float* wv = (const float*)d_in[3];
  const float* wo = (const float*)d_in[4];
  const float* cs = (const float*)d_in[5];
  const float* sn = (const float*)d_in[6];
  float* out = (float*)d_out;

  // Workspace layout (bf16 elems). wob aliases xb (xb dead after QKV GEMM);
  // Ab aliases Qb (flash O rows are block-local re-writes of its own Q rows).
  __hip_bfloat16* ws    = (__hip_bfloat16*)d_ws;
  __hip_bfloat16* xb    = ws;                         // M*D        = 16.78M
  __hip_bfloat16* wob   = ws;                         // alias of xb
  __hip_bfloat16* wqkvb = xb + M * D;                 // 6144*D     = 25.17M
  __hip_bfloat16* Qb    = wqkvb + 6144 * (size_t)D;   // M*NQ       = 16.78M
  __hip_bfloat16* Ab    = Qb;                         // alias of Qb
  __hip_bfloat16* Kb    = Qb + M * NQ;                // M*NKV      =  4.19M
  __hip_bfloat16* Vb    = Kb + M * NKV;               // M*NKV
  __hip_bfloat16* Vtb   = Vb + M * NKV;               // M*NKV      (~143 MB total)

  // 128 KiB dynamic LDS opt-in (one-time; host-side, graph-capture safe).
  static bool lds_attr_done = false;
  if (!lds_attr_done) {
    hipFuncSetAttribute(reinterpret_cast<const void*>(&gemm8p<0, 4096>),
                        hipFuncAttributeMaxDynamicSharedMemorySize, 131072);
    hipFuncSetAttribute(reinterpret_cast<const void*>(&gemm8p<1, 4096>),
                        hipFuncAttributeMaxDynamicSharedMemorySize, 131072);
    lds_attr_done = true;
  }

  dim3 blk(256);
  // fp32 -> bf16 conversions (pure BW, ~60 us total)
  cvt_bf16<<<1024, blk, 0, stream>>>(x,  xb,                    (long)(M * D));
  cvt_bf16<<<1024, blk, 0, stream>>>(wq, wqkvb,                 (long)(NQ * D));
  cvt_bf16<<<512,  blk, 0, stream>>>(wk, wqkvb + NQ * D,        (long)(NKV * D));
  cvt_bf16<<<512,  blk, 0, stream>>>(wv, wqkvb + (NQ + NKV) * D,(long)(NKV * D));

  // Fused QKV projection + RoPE (M=4096, N=6144), 256^2 8-phase
  gemm8p<0, 4096><<<dim3(24, 16), dim3(512), 131072, stream>>>(
      xb, wqkvb, Qb, Kb, Vb, nullptr, cs, sn);
  // wo conversion (after QKV GEMM: xb is dead, wob aliases it)
  cvt_bf16<<<1024, blk, 0, stream>>>(wo, wob, (long)(NQ * D));

  transpose_v<<<dim3(64, 4, 16), blk, 0, stream>>>(Vb, Vtb);
  flash_causal<<<dim3(16, 32, 2), blk, 0, stream>>>(Qb, Kb, Vtb, Ab);

  // Output projection (bf16 x bf16 -> fp32 out), 256^2 8-phase
  gemm8p<1, 4096><<<dim3(16, 16), dim3(512), 131072, stream>>>(
      Ab, wob, nullptr, nullptr, nullptr, out, nullptr, nullptr);
}